// Round 11
// baseline (454.259 us; speedup 1.0000x reference)
//
#include <hip/hip_runtime.h>

#define BATCH 8192
#define V 512
#define N1 513
#define KCH 16
#define NCHUNKS 32
#define RB 32            // rows per block -> grid 256, 1 block/CU
#define NT 512           // 8 waves; wave w: chain rows 4w..4w+3, j-tiles 4w..4w+3
#define PKS 520          // Phi row stride (bf16 elems)
#define SJ2 516          // S row stride (dwords)

typedef __bf16 bf16_t;
typedef bf16_t bf16x8 __attribute__((ext_vector_type(8)));
typedef float f32x4 __attribute__((ext_vector_type(4)));

// workspace: Mhi (fragment-linear triangular pack, mat=1 tiles PRE-NEGATED),
// Dv (fp32, pre-scaled by mat sign), Bv (fp32, pre-negated mat=1).
#define EPP 4194304ull
#define DV_OFF (EPP * 2ull)
#define BV_OFF (DV_OFF + 1048576ull)

__device__ __forceinline__ f32x4 mfma16(bf16x8 a, bf16x8 b, f32x4 c) {
    return __builtin_amdgcn_mfma_f32_16x16x32_bf16(a, b, c, 0, 0, 0);
}

__device__ __forceinline__ float bcast_lane(float x, int l) {
    return __int_as_float(__builtin_amdgcn_readlane(__float_as_int(x), l));
}

__device__ __forceinline__ float dpp_xor1_max(float x) {
    const int xi = __float_as_int(x);
    const float o = __int_as_float(
        __builtin_amdgcn_update_dpp(xi, xi, 0xB1, 0xF, 0xF, false));
    return fmaxf(x, o);
}

// ---- unified repack (unchanged from R5) -----------------------------------
__global__ __launch_bounds__(1024)
void repack_all(const float* __restrict__ pos, const float* __restrict__ neg,
                bf16_t* __restrict__ Mhi, float* __restrict__ Dv,
                float* __restrict__ Bv)
{
    __shared__ float sb[2 * 256 * 36];   // 73,728 B
    const int bx  = blockIdx.x;
    const int tid = threadIdx.x;
    if (bx < 496) {
        const int cc  = (bx >> 4) + 1;       // 1..31
        const int kb  = bx & 15;
        const int nkb = (cc + 1) >> 1;
        if (kb >= nkb) return;
        const int klen = 16 * cc;
        for (int idx = tid; idx < 8192; idx += 1024) {
            const int r = idx >> 5, k32 = idx & 31;
            const int k = kb * 32 + k32;
            const size_t row = (size_t)cc * 256 + r;
            float xp = 0.0f, xn = 0.0f;
            if (k < klen) {
                xp = pos[row * N1 + k];
                xn = -neg[row * N1 + k];     // pre-negate mat=1
            }
            sb[r * 36 + k32]            = xp;
            sb[256 * 36 + r * 36 + k32] = xn;
        }
        __syncthreads();
        const size_t base = 16384ull * (size_t)((cc * cc) / 4) + (size_t)kb * 16384ull;
        for (int e8 = tid; e8 < 2048; e8 += 1024) {
            const int t = e8 >> 6, s = e8 & 63;
            const int c = s & 15, q = s >> 4;
            const int vloc = t >> 1, m = t & 1;
            const float* sp = &sb[m * 256 * 36 + (vloc * 16 + c) * 36 + 8 * q];
            bf16x8 o;
            #pragma unroll
            for (int jj = 0; jj < 8; ++jj) o[jj] = (bf16_t)sp[jj];
            *(bf16x8*)(Mhi + base + (size_t)e8 * 8) = o;
        }
    } else {
        const int cc = bx - 496;             // 0..31, one block per chunk
        float* bufP = sb;                    // stride-17 views
        float* bufN = sb + 256 * 17;
        for (int idx = tid; idx < 4096; idx += 1024) {
            const int r = idx >> 4, kk = idx & 15;
            const size_t row = (size_t)(cc * 256 + r);
            bufP[r * 17 + kk] = pos[row * N1 + cc * 16 + kk];
            bufN[r * 17 + kk] = neg[row * N1 + cc * 16 + kk];
        }
        __syncthreads();
        for (int idx = tid; idx < 8192; idx += 1024) {
            const int vl = idx >> 9, j = idx & 511;
            const int vlo = j >> 5, c = j & 15;
            const int m = (j >> 4) & 1;
            const float x = (m ? bufN : bufP)[(vlo * 16 + c) * 17 + vl];
            Dv[(size_t)cc * 8192 + idx] = m ? -x : x;
        }
        for (int j = tid; j < 512; j += 1024) {
            const int vlo = j >> 5, c = j & 15;
            const int m = (j >> 4) & 1;
            const float* src = m ? neg : pos;
            const float x = src[(size_t)(cc * 256 + vlo * 16 + c) * N1 + V];
            Bv[(size_t)cc * 512 + j] = m ? -x : x;
        }
    }
}

// ---- fused main kernel R11: 8 waves, 4 rows + 4 j-tiles per wave -------------
// R9 resource audit: LDS pipe is the binding resource (~1060 of 1510 cy/step/CU)
// and the dv/fa reads are wave-invariant -> 16x redundant. Halving waves halves
// that traffic; per-wave VALU doubles (f32x4-packed rows) so total VALU/CU is
// unchanged. At 8 waves/CU (2/SIMD, launch_bounds(512,2)) the VGPR budget is
// 256/wave: the R2-R4 spill wall is gone, so fb is register-prefetched one
// k-block ahead (consume-then-load leaves the FINAL k-block in regs for the
// post-barrier read, incl. the nkbN==1 edge), dv one step ahead, po per-chunk.
// Numerics: identical per-row op order -> absmax 8.0.
// Spill tell: WRITE_SIZE >> 16.4 MB.
__global__ __launch_bounds__(NT, 2)
void shield_fused(const float* __restrict__ preds,
                  const bf16_t* __restrict__ Mhi,
                  const float* __restrict__ Dv, const float* __restrict__ Bv,
                  float* __restrict__ out)
{
    __shared__ bf16_t Phi[RB * PKS];   // 33,280 B
    __shared__ float  S[RB * SJ2];     // 66,048 B; [0:8192) doubles as Dv_lds
                                       // total 99,328 -> 1 block/CU

    const int tid  = threadIdx.x;
    const int b0   = blockIdx.x * RB;
    const int lane = tid & 63;
    const int w    = tid >> 6;          // 0..7
    const int cq   = lane & 15;
    const int q    = lane >> 4;
    const int rp0  = w * 4;             // chain rows 4w..4w+3

    // ---- load preds -> Phi: wave w loads rows 4w..4w+3, 8 cols/lane ----
    #pragma unroll
    for (int i = 0; i < 4; ++i) {
        const int row = rp0 + i;
        const float* prow = preds + (size_t)(b0 + row) * V + lane * 8;
        const float4 p0 = *(const float4*)(prow);
        const float4 p1 = *(const float4*)(prow + 4);
        const int n = lane * 8;
        Phi[row * PKS + n + 0] = (bf16_t)p0.x;
        Phi[row * PKS + n + 1] = (bf16_t)p0.y;
        Phi[row * PKS + n + 2] = (bf16_t)p0.z;
        Phi[row * PKS + n + 3] = (bf16_t)p0.w;
        Phi[row * PKS + n + 4] = (bf16_t)p1.x;
        Phi[row * PKS + n + 5] = (bf16_t)p1.y;
        Phi[row * PKS + n + 6] = (bf16_t)p1.z;
        Phi[row * PKS + n + 7] = (bf16_t)p1.w;
    }

    int tJ[4];
    #pragma unroll
    for (int tt = 0; tt < 4; ++tt) tJ[tt] = ((4 * w + tt) << 4) + cq;
    const int aoff0 = cq * PKS + 8 * q;
    const int aoff1 = (16 + cq) * PKS + 8 * q;

    // acc(0) = bias(0)
    f32x4 acc[2][4];
    #pragma unroll
    for (int tt = 0; tt < 4; ++tt) {
        const float b = Bv[tJ[tt]];
        acc[0][tt] = f32x4{b, b, b, b};
        acc[1][tt] = f32x4{b, b, b, b};
    }

    #pragma unroll 1
    for (int cc = 0; cc < NCHUNKS; ++cc) {
        const int v0 = cc * 16;
        const int  ccn  = cc + 1;
        const bool hasN = ccn < NCHUNKS;
        const int  nkbN = hasN ? ((ccn + 1) >> 1) : 0;
        const bf16_t* phN = Mhi + 16384ull * (size_t)((ccn * ccn) / 4)
                          + (size_t)lane * 8 + (size_t)(4 * w) * 512;

        // ---- dump acc(cc) -> S ----
        #pragma unroll
        for (int tt = 0; tt < 4; ++tt)
            #pragma unroll
            for (int reg = 0; reg < 4; ++reg) {
                S[(4 * q + reg) * SJ2 + tJ[tt]]      = acc[0][tt][reg];
                S[(16 + 4 * q + reg) * SJ2 + tJ[tt]] = acc[1][tt][reg];
            }
        __syncthreads();   // (A) S ready; prior Phi writes visible

        // ---- load s2: lane owns j = 8*lane..8*lane+7, rows 4w..4w+3 ----
        f32x4 s2[8];
        {
            const float* sp = &S[rp0 * SJ2 + 8 * lane];
            const float4 a0 = *(const float4*)(sp);
            const float4 a1 = *(const float4*)(sp + 4);
            const float4 b0_ = *(const float4*)(sp + SJ2);
            const float4 b1_ = *(const float4*)(sp + SJ2 + 4);
            const float4 c0 = *(const float4*)(sp + 2 * SJ2);
            const float4 c1 = *(const float4*)(sp + 2 * SJ2 + 4);
            const float4 d0 = *(const float4*)(sp + 3 * SJ2);
            const float4 d1 = *(const float4*)(sp + 3 * SJ2 + 4);
            s2[0] = f32x4{a0.x, b0_.x, c0.x, d0.x};
            s2[1] = f32x4{a0.y, b0_.y, c0.y, d0.y};
            s2[2] = f32x4{a0.z, b0_.z, c0.z, d0.z};
            s2[3] = f32x4{a0.w, b0_.w, c0.w, d0.w};
            s2[4] = f32x4{a1.x, b1_.x, c1.x, d1.x};
            s2[5] = f32x4{a1.y, b1_.y, c1.y, d1.y};
            s2[6] = f32x4{a1.z, b1_.z, c1.z, d1.z};
            s2[7] = f32x4{a1.w, b1_.w, c1.w, d1.w};
        }

        // ---- po prefetch: cols v0..v0+15 of rows 4w..4w+3 ----
        bf16x8 poL[4], poH[4];
        #pragma unroll
        for (int r = 0; r < 4; ++r) {
            poL[r] = *(const bf16x8*)(Phi + (rp0 + r) * PKS + v0);
            poH[r] = *(const bf16x8*)(Phi + (rp0 + r) * PKS + v0 + 8);
        }

        // ---- init acc(ccn) with bias ----
        if (hasN) {
            #pragma unroll
            for (int tt = 0; tt < 4; ++tt) {
                const float b = Bv[(ccn << 9) + tJ[tt]];
                acc[0][tt] = f32x4{b, b, b, b};
                acc[1][tt] = f32x4{b, b, b, b};
            }
        }

        // ---- fb prologue: k-block 0 into regs (budget 256 -> no spill) ----
        bf16x8 fbn0, fbn1, fbn2, fbn3;
        if (hasN) {
            fbn0 = *(const bf16x8*)(phN);
            fbn1 = *(const bf16x8*)(phN + 512);
            fbn2 = *(const bf16x8*)(phN + 1024);
            fbn3 = *(const bf16x8*)(phN + 1536);
        }

        __syncthreads();   // (B) all s2 reads done; S region reusable

        // ---- stage Dv(cc) into S[0:8192): wave w stages v-rows 2w, 2w+1 ----
        #pragma unroll
        for (int i = 0; i < 2; ++i) {
            const int vr = 2 * w + i;
            const float* src = Dv + (((size_t)cc * 16 + vr) << 9) + 8 * lane;
            const float4 a = *(const float4*)(src);
            const float4 b = *(const float4*)(src + 4);
            float* dst = S + vr * 512 + 8 * lane;
            *(float4*)(dst)     = a;
            *(float4*)(dst + 4) = b;
        }
        __syncthreads();   // (C) Dv_lds ready

        // ---- dv prologue: step 0 from LDS ----
        float dvn[8];
        {
            const float* dls = S + 8 * lane;
            const float4 d0 = *(const float4*)(dls);
            const float4 d1 = *(const float4*)(dls + 4);
            dvn[0]=d0.x; dvn[1]=d0.y; dvn[2]=d0.z; dvn[3]=d0.w;
            dvn[4]=d1.x; dvn[5]=d1.y; dvn[6]=d1.z; dvn[7]=d1.w;
        }

        // ---- 16-step serial chain + interleaved bulk GEMM of chunk ccn ----
        #pragma unroll
        for (int vl = 0; vl < KCH; ++vl) {
            const int vcur = v0 + vl;
            const bool doKb = hasN && (vl < nkbN - 1);

            // consume prefetched fb; prefetch k-block vl+1 (the last issue,
            // at vl==nkbN-2, loads the FINAL k-block and holds it for post-D)
            bf16x8 fb0, fb1, fb2, fb3, fa0, fa1;
            if (doKb) {
                fb0 = fbn0; fb1 = fbn1; fb2 = fbn2; fb3 = fbn3;
                const bf16_t* g = phN + (size_t)(vl + 1) * 16384;
                fbn0 = *(const bf16x8*)(g);
                fbn1 = *(const bf16x8*)(g + 512);
                fbn2 = *(const bf16x8*)(g + 1024);
                fbn3 = *(const bf16x8*)(g + 1536);
                const int k0 = vl * 32;
                fa0 = *(const bf16x8*)(Phi + aoff0 + k0);
                fa1 = *(const bf16x8*)(Phi + aoff1 + k0);
            }

            // consume prefetched dv; prefetch step vl+1 from LDS
            float dvc[8];
            #pragma unroll
            for (int jj = 0; jj < 8; ++jj) dvc[jj] = dvn[jj];
            if (vl + 1 < KCH) {
                const float* dls = S + (vl + 1) * 512 + 8 * lane;
                const float4 d0 = *(const float4*)(dls);
                const float4 d1 = *(const float4*)(dls + 4);
                dvn[0]=d0.x; dvn[1]=d0.y; dvn[2]=d0.z; dvn[3]=d0.w;
                dvn[4]=d1.x; dvn[5]=d1.y; dvn[6]=d1.z; dvn[7]=d1.w;
            }

            // packed in-lane reduce 8 -> 1 (4 rows at once), xor-1 merge (DPP)
            const f32x4 m01 = __builtin_elementwise_max(s2[0], s2[1]);
            const f32x4 m23 = __builtin_elementwise_max(s2[2], s2[3]);
            const f32x4 m45 = __builtin_elementwise_max(s2[4], s2[5]);
            const f32x4 m67 = __builtin_elementwise_max(s2[6], s2[7]);
            const f32x4 mx  = __builtin_elementwise_max(
                                  __builtin_elementwise_max(m01, m23),
                                  __builtin_elementwise_max(m45, m67));
            float pc[4];
            #pragma unroll
            for (int r = 0; r < 4; ++r) {
                const float red = dpp_xor1_max(mx[r]);
                const float lw  = bcast_lane(red, 4 * vl);       // lower
                const float nup = bcast_lane(red, 4 * vl + 2);   // -upper
                const float po  = (float)(vl < 8 ? poL[r][vl & 7]
                                                 : poH[r][vl & 7]);
                pc[r] = fminf(fmaxf(po, lw), -nup);
            }
            if (lane == 4 * vl) {
                #pragma unroll
                for (int r = 0; r < 4; ++r)
                    Phi[(rp0 + r) * PKS + vcur] = (bf16_t)pc[r];
            }
            // rank-1 update (packed f32x4; Dv pre-scaled so no sign mul)
            const f32x4 pcv = {pc[0], pc[1], pc[2], pc[3]};
            #pragma unroll
            for (int jj = 0; jj < 8; ++jj) {
                const f32x4 dsp = {dvc[jj], dvc[jj], dvc[jj], dvc[jj]};
                s2[jj] = __builtin_elementwise_fma(dsp, pcv, s2[jj]);
            }

            if (doKb) {
                acc[0][0] = mfma16(fa0, fb0, acc[0][0]);
                acc[1][0] = mfma16(fa1, fb0, acc[1][0]);
                acc[0][1] = mfma16(fa0, fb1, acc[0][1]);
                acc[1][1] = mfma16(fa1, fb1, acc[1][1]);
                acc[0][2] = mfma16(fa0, fb2, acc[0][2]);
                acc[1][2] = mfma16(fa1, fb2, acc[1][2]);
                acc[0][3] = mfma16(fa0, fb3, acc[0][3]);
                acc[1][3] = mfma16(fa1, fb3, acc[1][3]);
            }
        }

        __syncthreads();   // (D) fresh Phi visible; S safe for next dump

        // ---- final k-block: fb held in fbn regs; fa reads FRESH Phi ----
        if (hasN) {
            const int k0 = (nkbN - 1) * 32;
            const bf16x8 fa0 = *(const bf16x8*)(Phi + aoff0 + k0);
            const bf16x8 fa1 = *(const bf16x8*)(Phi + aoff1 + k0);
            acc[0][0] = mfma16(fa0, fbn0, acc[0][0]);
            acc[1][0] = mfma16(fa1, fbn0, acc[1][0]);
            acc[0][1] = mfma16(fa0, fbn1, acc[0][1]);
            acc[1][1] = mfma16(fa1, fbn1, acc[1][1]);
            acc[0][2] = mfma16(fa0, fbn2, acc[0][2]);
            acc[1][2] = mfma16(fa1, fbn2, acc[1][2]);
            acc[0][3] = mfma16(fa0, fbn3, acc[0][3]);
            acc[1][3] = mfma16(fa1, fbn3, acc[1][3]);
        }
    }

    // ---- epilogue: wave w writes rows 4w..4w+3, 8 cols/lane, coalesced ----
    #pragma unroll
    for (int i = 0; i < 4; ++i) {
        const int row = rp0 + i;
        float* orow = out + (size_t)(b0 + row) * V + lane * 8;
        const int n = lane * 8;
        float4 o0, o1;
        o0.x = (float)Phi[row * PKS + n + 0];
        o0.y = (float)Phi[row * PKS + n + 1];
        o0.z = (float)Phi[row * PKS + n + 2];
        o0.w = (float)Phi[row * PKS + n + 3];
        o1.x = (float)Phi[row * PKS + n + 4];
        o1.y = (float)Phi[row * PKS + n + 5];
        o1.z = (float)Phi[row * PKS + n + 6];
        o1.w = (float)Phi[row * PKS + n + 7];
        *(float4*)(orow)     = o0;
        *(float4*)(orow + 4) = o1;
    }
}

extern "C" void kernel_launch(void* const* d_in, const int* in_sizes, int n_in,
                              void* d_out, int out_size, void* d_ws, size_t ws_size,
                              hipStream_t stream) {
    const float* preds = (const float*)d_in[0];
    const float* pos   = (const float*)d_in[1];
    const float* neg   = (const float*)d_in[2];
    float* o = (float*)d_out;
    char* base = (char*)d_ws;
    bf16_t* Mhi = (bf16_t*)base;
    float*  Dv  = (float*)(base + DV_OFF);
    float*  Bv  = (float*)(base + BV_OFF);
    repack_all<<<dim3(528), 1024, 0, stream>>>(pos, neg, Mhi, Dv, Bv);
    shield_fused<<<dim3(BATCH / RB), NT, 0, stream>>>(preds, Mhi, Dv, Bv, o);
}

// Round 12
// 402.366 us; speedup vs baseline: 1.1290x; 1.1290x over previous
//
#include <hip/hip_runtime.h>

#define BATCH 8192
#define V 512
#define N1 513
#define KCH 16
#define NCHUNKS 32
#define RB 16            // rows per block -> grid 512 = 2 blocks/CU, 32 waves/CU
#define NT 1024          // 16 waves; each wave owns ONE chain row
#define PKS 512          // Phi row stride (bf16) -- shrunk so all 3 regions fit
#define SJ2 512          // S row stride (dwords)

typedef __bf16 bf16_t;
typedef bf16_t bf16x8 __attribute__((ext_vector_type(8)));
typedef float f32x4 __attribute__((ext_vector_type(4)));

// workspace: Mhi (fragment-linear triangular pack, mat=1 tiles PRE-NEGATED),
// Dv (fp32, pre-scaled by mat sign), Bv (fp32, pre-negated mat=1).
#define EPP 4194304ull
#define DV_OFF (EPP * 2ull)
#define BV_OFF (DV_OFF + 1048576ull)

__device__ __forceinline__ f32x4 mfma16(bf16x8 a, bf16x8 b, f32x4 c) {
    return __builtin_amdgcn_mfma_f32_16x16x32_bf16(a, b, c, 0, 0, 0);
}

__device__ __forceinline__ float bcast_lane(float x, int l) {
    return __int_as_float(__builtin_amdgcn_readlane(__float_as_int(x), l));
}

__device__ __forceinline__ float dpp_xor1_max(float x) {
    const int xi = __float_as_int(x);
    const float o = __int_as_float(
        __builtin_amdgcn_update_dpp(xi, xi, 0xB1, 0xF, 0xF, false));
    return fmaxf(x, o);
}

// ---- unified repack (R5 + vectorized Mhi output LDS gather) ----------------
__global__ __launch_bounds__(1024)
void repack_all(const float* __restrict__ pos, const float* __restrict__ neg,
                bf16_t* __restrict__ Mhi, float* __restrict__ Dv,
                float* __restrict__ Bv)
{
    __shared__ float sb[2 * 256 * 36];   // 73,728 B
    const int bx  = blockIdx.x;
    const int tid = threadIdx.x;
    if (bx < 496) {
        const int cc  = (bx >> 4) + 1;       // 1..31
        const int kb  = bx & 15;
        const int nkb = (cc + 1) >> 1;
        if (kb >= nkb) return;
        const int klen = 16 * cc;
        for (int idx = tid; idx < 8192; idx += 1024) {
            const int r = idx >> 5, k32 = idx & 31;
            const int k = kb * 32 + k32;
            const size_t row = (size_t)cc * 256 + r;
            float xp = 0.0f, xn = 0.0f;
            if (k < klen) {
                xp = pos[row * N1 + k];
                xn = -neg[row * N1 + k];     // pre-negate mat=1
            }
            sb[r * 36 + k32]            = xp;
            sb[256 * 36 + r * 36 + k32] = xn;
        }
        __syncthreads();
        const size_t base = 16384ull * (size_t)((cc * cc) / 4) + (size_t)kb * 16384ull;
        for (int e8 = tid; e8 < 2048; e8 += 1024) {
            const int t = e8 >> 6, s = e8 & 63;
            const int c = s & 15, q = s >> 4;
            const int vloc = t >> 1, m = t & 1;
            // 16B-aligned gather: (vloc*16+c)*36 + 8q ≡ 0 mod 4
            const float* sp = &sb[m * 256 * 36 + (vloc * 16 + c) * 36 + 8 * q];
            const float4 f0 = *(const float4*)(sp);
            const float4 f1 = *(const float4*)(sp + 4);
            bf16x8 o;
            o[0] = (bf16_t)f0.x; o[1] = (bf16_t)f0.y;
            o[2] = (bf16_t)f0.z; o[3] = (bf16_t)f0.w;
            o[4] = (bf16_t)f1.x; o[5] = (bf16_t)f1.y;
            o[6] = (bf16_t)f1.z; o[7] = (bf16_t)f1.w;
            *(bf16x8*)(Mhi + base + (size_t)e8 * 8) = o;
        }
    } else {
        const int cc = bx - 496;             // 0..31, one block per chunk
        float* bufP = sb;                    // stride-17 views
        float* bufN = sb + 256 * 17;
        for (int idx = tid; idx < 4096; idx += 1024) {
            const int r = idx >> 4, kk = idx & 15;
            const size_t row = (size_t)(cc * 256 + r);
            bufP[r * 17 + kk] = pos[row * N1 + cc * 16 + kk];
            bufN[r * 17 + kk] = neg[row * N1 + cc * 16 + kk];
        }
        __syncthreads();
        for (int idx = tid; idx < 8192; idx += 1024) {
            const int vl = idx >> 9, j = idx & 511;
            const int vlo = j >> 5, c = j & 15;
            const int m = (j >> 4) & 1;
            const float x = (m ? bufN : bufP)[(vlo * 16 + c) * 17 + vl];
            Dv[(size_t)cc * 8192 + idx] = m ? -x : x;
        }
        for (int j = tid; j < 512; j += 1024) {
            const int vlo = j >> 5, c = j & 15;
            const int m = (j >> 4) & 1;
            const float* src = m ? neg : pos;
            const float x = src[(size_t)(cc * 256 + vlo * 16 + c) * N1 + V];
            Bv[(size_t)cc * 512 + j] = m ? -x : x;
        }
    }
}

// ---- fused main kernel R12: R7 structure, 2 barriers/chunk -------------------
// R7/R9/R11 established TLP (32 waves/CU) as the dominant lever; conflicts and
// register prefetch are nulls. Remaining R7 overhead: 4 barriers/chunk plus an
// exposed Dv stage between B and C (S-alias forced it). Fix: dedicated Dv_lds
// region (PKS/SJ2 shrunk to 512 so Phi 16,384 + S 32,768 + Dvl 32,768 =
// 81,920 B exactly -> still 2 blocks/CU). Dv(cc+1) is staged AFTER barrier D,
// overlapped with the final k-block + acc dump, covered by the next A ->
// barriers B and C are gone (2/chunk). fa becomes ~16-phase and the dump
// 4-way -- accepted on direct evidence (R8 phase-fix null, R11 conflict-halving
// null; LDS pipe has slack). Races audited: in-chain fa cols <= 16cc-1 < v0;
// every wave's s2 read precedes its D so the next dump is safe; Dvl consumed
// before D, rewritten after D, visible by A. Numerics identical -> absmax 8.0.
// Spill tell: WRITE_SIZE >> 16.4 MB.
__global__ __launch_bounds__(NT, 8)
void shield_fused(const float* __restrict__ preds,
                  const bf16_t* __restrict__ Mhi,
                  const float* __restrict__ Dv, const float* __restrict__ Bv,
                  float* __restrict__ out)
{
    __shared__ bf16_t Phi[RB * PKS];   // 16,384 B
    __shared__ float  S[RB * SJ2];     // 32,768 B
    __shared__ float  Dvl[16 * 512];   // 32,768 B   (total 81,920 -> 2/CU)

    const int tid  = threadIdx.x;
    const int b0   = blockIdx.x * RB;
    const int lane = tid & 63;
    const int w    = tid >> 6;          // 0..15; chain row = w
    const int cq   = lane & 15;
    const int q    = lane >> 4;

    // ---- load preds -> Phi: wave w loads its row, 8 cols/lane, coalesced ----
    {
        const float* prow = preds + (size_t)(b0 + w) * V + lane * 8;
        const float4 p0 = *(const float4*)(prow);
        const float4 p1 = *(const float4*)(prow + 4);
        const int n = lane * 8;
        Phi[w * PKS + n + 0] = (bf16_t)p0.x;
        Phi[w * PKS + n + 1] = (bf16_t)p0.y;
        Phi[w * PKS + n + 2] = (bf16_t)p0.z;
        Phi[w * PKS + n + 3] = (bf16_t)p0.w;
        Phi[w * PKS + n + 4] = (bf16_t)p1.x;
        Phi[w * PKS + n + 5] = (bf16_t)p1.y;
        Phi[w * PKS + n + 6] = (bf16_t)p1.z;
        Phi[w * PKS + n + 7] = (bf16_t)p1.w;
    }

    int tJ[2];
    #pragma unroll
    for (int tt = 0; tt < 2; ++tt) tJ[tt] = ((2 * w + tt) << 4) + cq;
    const int aoff = cq * PKS + 8 * q;

    // acc(0) = bias(0)
    f32x4 acc[2];
    #pragma unroll
    for (int tt = 0; tt < 2; ++tt) {
        const float b = Bv[tJ[tt]];
        acc[tt] = f32x4{b, b, b, b};
    }

    // ---- prologue: stage Dv(0) into Dvl (visible at first barrier A) ----
    {
        const float* src = Dv + ((size_t)w << 9) + 8 * lane;
        const float4 a = *(const float4*)(src);
        const float4 b = *(const float4*)(src + 4);
        float* dst = Dvl + w * 512 + 8 * lane;
        *(float4*)(dst)     = a;
        *(float4*)(dst + 4) = b;
    }

    #pragma unroll 1
    for (int cc = 0; cc < NCHUNKS; ++cc) {
        const int v0 = cc * 16;
        const int  ccn  = cc + 1;
        const bool hasN = ccn < NCHUNKS;
        const int  nkbN = hasN ? ((ccn + 1) >> 1) : 0;
        const bf16_t* phN = Mhi + 16384ull * (size_t)((ccn * ccn) / 4)
                          + (size_t)lane * 8 + (size_t)(2 * w) * 512;

        // ---- dump acc(cc) -> S ----
        #pragma unroll
        for (int tt = 0; tt < 2; ++tt)
            #pragma unroll
            for (int reg = 0; reg < 4; ++reg)
                S[(4 * q + reg) * SJ2 + tJ[tt]] = acc[tt][reg];
        __syncthreads();   // (A) S + Dvl(cc) + fresh Phi all visible

        // ---- load s2: lane owns j = 8*lane..8*lane+7 of row w ----
        float s2[8];
        {
            const float* sp = &S[w * SJ2 + 8 * lane];
            const float4 a0 = *(const float4*)(sp);
            const float4 a1 = *(const float4*)(sp + 4);
            s2[0] = a0.x; s2[1] = a0.y; s2[2] = a0.z; s2[3] = a0.w;
            s2[4] = a1.x; s2[5] = a1.y; s2[6] = a1.z; s2[7] = a1.w;
        }

        // ---- po prefetch: cols v0..v0+15 of row w ----
        const bf16x8 po0 = *(const bf16x8*)(Phi + w * PKS + v0);
        const bf16x8 po1 = *(const bf16x8*)(Phi + w * PKS + v0 + 8);

        // ---- init acc(ccn) with bias ----
        if (hasN) {
            #pragma unroll
            for (int tt = 0; tt < 2; ++tt) {
                const float b = Bv[(ccn << 9) + tJ[tt]];
                acc[tt] = f32x4{b, b, b, b};
            }
        }

        // ---- 16-step serial chain + interleaved bulk GEMM of chunk ccn ----
        #pragma unroll
        for (int vl = 0; vl < KCH; ++vl) {
            const int vcur = v0 + vl;
            const bool doKb = hasN && (vl < nkbN - 1);

            bf16x8 fa, fb0, fb1;
            if (doKb) {
                const int k0 = vl * 32;
                fa  = *(const bf16x8*)(Phi + aoff + k0);
                const bf16_t* pb = phN + (size_t)k0 * 512;
                fb0 = *(const bf16x8*)(pb);
                fb1 = *(const bf16x8*)(pb + 512);
            }

            // this step's dv from Dvl (shared across all 16 waves)
            float dv[8];
            {
                const float* dls = Dvl + vl * 512 + 8 * lane;
                const float4 d0 = *(const float4*)(dls);
                const float4 d1 = *(const float4*)(dls + 4);
                dv[0]=d0.x; dv[1]=d0.y; dv[2]=d0.z; dv[3]=d0.w;
                dv[4]=d1.x; dv[5]=d1.y; dv[6]=d1.z; dv[7]=d1.w;
            }
            const float po = (float)(vl < 8 ? po0[vl & 7] : po1[vl & 7]);

            // in-lane reduce 8 -> 1 (max3-fusable), xor-1 merge via DPP
            const float m0 = fmaxf(fmaxf(s2[0], s2[1]), s2[2]);
            const float m1 = fmaxf(fmaxf(s2[3], s2[4]), s2[5]);
            const float m2 = fmaxf(s2[6], s2[7]);
            const float red = dpp_xor1_max(fmaxf(fmaxf(m0, m1), m2));
            // broadcast from compile-time lanes via v_readlane (no DS op)
            const float lw  = bcast_lane(red, 4 * vl);       // lower
            const float nup = bcast_lane(red, 4 * vl + 2);   // -upper
            const float pc  = fminf(fmaxf(po, lw), -nup);
            if (lane == 4 * vl) Phi[w * PKS + vcur] = (bf16_t)pc;

            // rank-1 update (Dv pre-scaled so no sign mul)
            #pragma unroll
            for (int jj = 0; jj < 8; ++jj) s2[jj] = fmaf(dv[jj], pc, s2[jj]);

            if (doKb) {
                acc[0] = mfma16(fa, fb0, acc[0]);
                acc[1] = mfma16(fa, fb1, acc[1]);
            }
        }

        __syncthreads();   // (D) chain done: fresh Phi visible; Dvl consumed;
                           //     S consumed (s2 reads were pre-chain)

        // ---- final k-block of chunk ccn (zero-padded B -> exact no-ops) ----
        if (hasN) {
            const int k0 = (nkbN - 1) * 32;
            const bf16x8 fa  = *(const bf16x8*)(Phi + aoff + k0);
            const bf16_t* pb = phN + (size_t)k0 * 512;
            const bf16x8 fb0 = *(const bf16x8*)(pb);
            const bf16x8 fb1 = *(const bf16x8*)(pb + 512);
            acc[0] = mfma16(fa, fb0, acc[0]);
            acc[1] = mfma16(fa, fb1, acc[1]);
        }

        // ---- stage Dv(ccn) into Dvl: overlapped with final-kb + next dump,
        //      visible at the next barrier A ----
        if (hasN) {
            const float* src = Dv + (((size_t)ccn * 16 + w) << 9) + 8 * lane;
            const float4 a = *(const float4*)(src);
            const float4 b = *(const float4*)(src + 4);
            float* dst = Dvl + w * 512 + 8 * lane;
            *(float4*)(dst)     = a;
            *(float4*)(dst + 4) = b;
        }
    }

    // ---- epilogue: wave w writes its row, 8 cols/lane, coalesced ----
    {
        float* orow = out + (size_t)(b0 + w) * V + lane * 8;
        const int n = lane * 8;
        float4 o0, o1;
        o0.x = (float)Phi[w * PKS + n + 0];
        o0.y = (float)Phi[w * PKS + n + 1];
        o0.z = (float)Phi[w * PKS + n + 2];
        o0.w = (float)Phi[w * PKS + n + 3];
        o1.x = (float)Phi[w * PKS + n + 4];
        o1.y = (float)Phi[w * PKS + n + 5];
        o1.z = (float)Phi[w * PKS + n + 6];
        o1.w = (float)Phi[w * PKS + n + 7];
        *(float4*)(orow)     = o0;
        *(float4*)(orow + 4) = o1;
    }
}

extern "C" void kernel_launch(void* const* d_in, const int* in_sizes, int n_in,
                              void* d_out, int out_size, void* d_ws, size_t ws_size,
                              hipStream_t stream) {
    const float* preds = (const float*)d_in[0];
    const float* pos   = (const float*)d_in[1];
    const float* neg   = (const float*)d_in[2];
    float* o = (float*)d_out;
    char* base = (char*)d_ws;
    bf16_t* Mhi = (bf16_t*)base;
    float*  Dv  = (float*)(base + DV_OFF);
    float*  Bv  = (float*)(base + BV_OFF);
    repack_all<<<dim3(528), 1024, 0, stream>>>(pos, neg, Mhi, Dv, Bv);
    shield_fused<<<dim3(BATCH / RB), NT, 0, stream>>>(preds, Mhi, Dv, Bv, o);
}

// Round 13
// 381.103 us; speedup vs baseline: 1.1920x; 1.0558x over previous
//
#include <hip/hip_runtime.h>

#define BATCH 8192
#define V 512
#define N1 513
#define KCH 16
#define NCHUNKS 32
#define RB 16            // rows per block -> grid 512 = 2 blocks/CU, 32 waves/CU
#define NT 1024          // 16 waves; each wave owns ONE chain row
#define PKS 512          // Phi row stride (bf16); fa de-conflicted by rotation
#define SJ2 512          // S row stride (dwords)

typedef __bf16 bf16_t;
typedef bf16_t bf16x8 __attribute__((ext_vector_type(8)));
typedef float f32x4 __attribute__((ext_vector_type(4)));

// workspace: Mhi (fragment-linear triangular pack, mat=1 tiles PRE-NEGATED),
// Dv (fp32, pre-scaled by mat sign), Bv (fp32, pre-negated mat=1).
#define EPP 4194304ull
#define DV_OFF (EPP * 2ull)
#define BV_OFF (DV_OFF + 1048576ull)

__device__ __forceinline__ f32x4 mfma16(bf16x8 a, bf16x8 b, f32x4 c) {
    return __builtin_amdgcn_mfma_f32_16x16x32_bf16(a, b, c, 0, 0, 0);
}

__device__ __forceinline__ float bcast_lane(float x, int l) {
    return __int_as_float(__builtin_amdgcn_readlane(__float_as_int(x), l));
}

__device__ __forceinline__ float dpp_xor1_max(float x) {
    const int xi = __float_as_int(x);
    const float o = __int_as_float(
        __builtin_amdgcn_update_dpp(xi, xi, 0xB1, 0xF, 0xF, false));
    return fmaxf(x, o);
}

// Phi cyclic block rotation: 16B-block cb of row r lives at slot (cb+r)&63.
// Restores fa's 8-phase access at PKS=512 (row base ≡ 0 mod 128B would
// otherwise collapse it to 16 phases -- the R12 regression).
__device__ __forceinline__ int phi_blk(int row, int cb) {
    return row * PKS + (((cb + row) & 63) << 3);
}
__device__ __forceinline__ int phi_col(int row, int col) {
    return phi_blk(row, col >> 3) + (col & 7);
}

// ---- unified repack (R12: vectorized Mhi output LDS gather) ----------------
__global__ __launch_bounds__(1024)
void repack_all(const float* __restrict__ pos, const float* __restrict__ neg,
                bf16_t* __restrict__ Mhi, float* __restrict__ Dv,
                float* __restrict__ Bv)
{
    __shared__ float sb[2 * 256 * 36];   // 73,728 B
    const int bx  = blockIdx.x;
    const int tid = threadIdx.x;
    if (bx < 496) {
        const int cc  = (bx >> 4) + 1;       // 1..31
        const int kb  = bx & 15;
        const int nkb = (cc + 1) >> 1;
        if (kb >= nkb) return;
        const int klen = 16 * cc;
        for (int idx = tid; idx < 8192; idx += 1024) {
            const int r = idx >> 5, k32 = idx & 31;
            const int k = kb * 32 + k32;
            const size_t row = (size_t)cc * 256 + r;
            float xp = 0.0f, xn = 0.0f;
            if (k < klen) {
                xp = pos[row * N1 + k];
                xn = -neg[row * N1 + k];     // pre-negate mat=1
            }
            sb[r * 36 + k32]            = xp;
            sb[256 * 36 + r * 36 + k32] = xn;
        }
        __syncthreads();
        const size_t base = 16384ull * (size_t)((cc * cc) / 4) + (size_t)kb * 16384ull;
        for (int e8 = tid; e8 < 2048; e8 += 1024) {
            const int t = e8 >> 6, s = e8 & 63;
            const int c = s & 15, q = s >> 4;
            const int vloc = t >> 1, m = t & 1;
            const float* sp = &sb[m * 256 * 36 + (vloc * 16 + c) * 36 + 8 * q];
            const float4 f0 = *(const float4*)(sp);
            const float4 f1 = *(const float4*)(sp + 4);
            bf16x8 o;
            o[0] = (bf16_t)f0.x; o[1] = (bf16_t)f0.y;
            o[2] = (bf16_t)f0.z; o[3] = (bf16_t)f0.w;
            o[4] = (bf16_t)f1.x; o[5] = (bf16_t)f1.y;
            o[6] = (bf16_t)f1.z; o[7] = (bf16_t)f1.w;
            *(bf16x8*)(Mhi + base + (size_t)e8 * 8) = o;
        }
    } else {
        const int cc = bx - 496;             // 0..31, one block per chunk
        float* bufP = sb;                    // stride-17 views
        float* bufN = sb + 256 * 17;
        for (int idx = tid; idx < 4096; idx += 1024) {
            const int r = idx >> 4, kk = idx & 15;
            const size_t row = (size_t)(cc * 256 + r);
            bufP[r * 17 + kk] = pos[row * N1 + cc * 16 + kk];
            bufN[r * 17 + kk] = neg[row * N1 + cc * 16 + kk];
        }
        __syncthreads();
        for (int idx = tid; idx < 8192; idx += 1024) {
            const int vl = idx >> 9, j = idx & 511;
            const int vlo = j >> 5, c = j & 15;
            const int m = (j >> 4) & 1;
            const float x = (m ? bufN : bufP)[(vlo * 16 + c) * 17 + vl];
            Dv[(size_t)cc * 8192 + idx] = m ? -x : x;
        }
        for (int j = tid; j < 512; j += 1024) {
            const int vlo = j >> 5, c = j & 15;
            const int m = (j >> 4) & 1;
            const float* src = m ? neg : pos;
            const float x = src[(size_t)(cc * 256 + vlo * 16 + c) * N1 + V];
            Bv[(size_t)cc * 512 + j] = m ? -x : x;
        }
    }
}

// ---- fused main kernel R13: R12's 2-barrier structure + Phi block rotation ---
// R12 regressed purely on fa bank conflicts (1.0e8 vs R7's 4.6e7): PKS=512 put
// row bases ≡ 0 mod 128B -> fa = 16 phases (2x its volume minimum). Fix at
// zero LDS cost: cyclic 16B-block rotation (cb+row)&63 inside each Phi row ->
// fa start slot (cq+q+4vl)&7 -> optimal 8 phases. dv/s2/dump are already at
// their data-volume minimum (not fixable, per R8/R11 nulls). LDS stays
// 81,920 B exactly -> 2 blocks/CU, 32 waves/CU (the dominant lever).
// Structure per chunk: dump -> A -> s2/po -> chain (dv from Dvl) -> D ->
// final k-block + stage Dv(cc+1) into Dvl (covered by next A).
// Races as audited in R12. Numerics identical -> absmax 8.0.
__global__ __launch_bounds__(NT, 8)
void shield_fused(const float* __restrict__ preds,
                  const bf16_t* __restrict__ Mhi,
                  const float* __restrict__ Dv, const float* __restrict__ Bv,
                  float* __restrict__ out)
{
    __shared__ bf16_t Phi[RB * PKS];   // 16,384 B (rotated block layout)
    __shared__ float  S[RB * SJ2];     // 32,768 B
    __shared__ float  Dvl[16 * 512];   // 32,768 B   (total 81,920 -> 2/CU)

    const int tid  = threadIdx.x;
    const int b0   = blockIdx.x * RB;
    const int lane = tid & 63;
    const int w    = tid >> 6;          // 0..15; chain row = w
    const int cq   = lane & 15;
    const int q    = lane >> 4;

    // ---- load preds -> Phi: wave w, block lane -> rotated slot ----
    {
        const float* prow = preds + (size_t)(b0 + w) * V + lane * 8;
        const float4 p0 = *(const float4*)(prow);
        const float4 p1 = *(const float4*)(prow + 4);
        bf16x8 o;
        o[0] = (bf16_t)p0.x; o[1] = (bf16_t)p0.y;
        o[2] = (bf16_t)p0.z; o[3] = (bf16_t)p0.w;
        o[4] = (bf16_t)p1.x; o[5] = (bf16_t)p1.y;
        o[6] = (bf16_t)p1.z; o[7] = (bf16_t)p1.w;
        *(bf16x8*)(Phi + phi_blk(w, lane)) = o;
    }

    int tJ[2];
    #pragma unroll
    for (int tt = 0; tt < 2; ++tt) tJ[tt] = ((2 * w + tt) << 4) + cq;

    // acc(0) = bias(0)
    f32x4 acc[2];
    #pragma unroll
    for (int tt = 0; tt < 2; ++tt) {
        const float b = Bv[tJ[tt]];
        acc[tt] = f32x4{b, b, b, b};
    }

    // ---- prologue: stage Dv(0) into Dvl (visible at first barrier A) ----
    {
        const float* src = Dv + ((size_t)w << 9) + 8 * lane;
        const float4 a = *(const float4*)(src);
        const float4 b = *(const float4*)(src + 4);
        float* dst = Dvl + w * 512 + 8 * lane;
        *(float4*)(dst)     = a;
        *(float4*)(dst + 4) = b;
    }

    #pragma unroll 1
    for (int cc = 0; cc < NCHUNKS; ++cc) {
        const int v0 = cc * 16;
        const int  ccn  = cc + 1;
        const bool hasN = ccn < NCHUNKS;
        const int  nkbN = hasN ? ((ccn + 1) >> 1) : 0;
        const bf16_t* phN = Mhi + 16384ull * (size_t)((ccn * ccn) / 4)
                          + (size_t)lane * 8 + (size_t)(2 * w) * 512;

        // ---- dump acc(cc) -> S ----
        #pragma unroll
        for (int tt = 0; tt < 2; ++tt)
            #pragma unroll
            for (int reg = 0; reg < 4; ++reg)
                S[(4 * q + reg) * SJ2 + tJ[tt]] = acc[tt][reg];
        __syncthreads();   // (A) S + Dvl(cc) + fresh Phi all visible

        // ---- load s2: lane owns j = 8*lane..8*lane+7 of row w ----
        float s2[8];
        {
            const float* sp = &S[w * SJ2 + 8 * lane];
            const float4 a0 = *(const float4*)(sp);
            const float4 a1 = *(const float4*)(sp + 4);
            s2[0] = a0.x; s2[1] = a0.y; s2[2] = a0.z; s2[3] = a0.w;
            s2[4] = a1.x; s2[5] = a1.y; s2[6] = a1.z; s2[7] = a1.w;
        }

        // ---- po prefetch: blocks 2cc, 2cc+1 of row w (rotated slots) ----
        const bf16x8 po0 = *(const bf16x8*)(Phi + phi_blk(w, 2 * cc));
        const bf16x8 po1 = *(const bf16x8*)(Phi + phi_blk(w, 2 * cc + 1));

        // ---- init acc(ccn) with bias ----
        if (hasN) {
            #pragma unroll
            for (int tt = 0; tt < 2; ++tt) {
                const float b = Bv[(ccn << 9) + tJ[tt]];
                acc[tt] = f32x4{b, b, b, b};
            }
        }

        // ---- 16-step serial chain + interleaved bulk GEMM of chunk ccn ----
        #pragma unroll
        for (int vl = 0; vl < KCH; ++vl) {
            const int vcur = v0 + vl;
            const bool doKb = hasN && (vl < nkbN - 1);

            bf16x8 fa, fb0, fb1;
            if (doKb) {
                // fa row = cq, col-block = q + 4*vl -> rotated slot (8-phase)
                fa  = *(const bf16x8*)(Phi + phi_blk(cq, q + 4 * vl));
                const bf16_t* pb = phN + (size_t)(vl * 32) * 512;
                fb0 = *(const bf16x8*)(pb);
                fb1 = *(const bf16x8*)(pb + 512);
            }

            // this step's dv from Dvl (shared across all 16 waves)
            float dv[8];
            {
                const float* dls = Dvl + vl * 512 + 8 * lane;
                const float4 d0 = *(const float4*)(dls);
                const float4 d1 = *(const float4*)(dls + 4);
                dv[0]=d0.x; dv[1]=d0.y; dv[2]=d0.z; dv[3]=d0.w;
                dv[4]=d1.x; dv[5]=d1.y; dv[6]=d1.z; dv[7]=d1.w;
            }
            const float po = (float)(vl < 8 ? po0[vl & 7] : po1[vl & 7]);

            // in-lane reduce 8 -> 1 (max3-fusable), xor-1 merge via DPP
            const float m0 = fmaxf(fmaxf(s2[0], s2[1]), s2[2]);
            const float m1 = fmaxf(fmaxf(s2[3], s2[4]), s2[5]);
            const float m2 = fmaxf(s2[6], s2[7]);
            const float red = dpp_xor1_max(fmaxf(fmaxf(m0, m1), m2));
            // broadcast from compile-time lanes via v_readlane (no DS op)
            const float lw  = bcast_lane(red, 4 * vl);       // lower
            const float nup = bcast_lane(red, 4 * vl + 2);   // -upper
            const float pc  = fminf(fmaxf(po, lw), -nup);
            if (lane == 4 * vl) Phi[phi_col(w, vcur)] = (bf16_t)pc;

            // rank-1 update (Dv pre-scaled so no sign mul)
            #pragma unroll
            for (int jj = 0; jj < 8; ++jj) s2[jj] = fmaf(dv[jj], pc, s2[jj]);

            if (doKb) {
                acc[0] = mfma16(fa, fb0, acc[0]);
                acc[1] = mfma16(fa, fb1, acc[1]);
            }
        }

        __syncthreads();   // (D) chain done: fresh Phi visible; Dvl consumed;
                           //     S consumed (s2 reads were pre-chain)

        // ---- final k-block of chunk ccn (zero-padded B -> exact no-ops) ----
        if (hasN) {
            const int kbF = nkbN - 1;
            const bf16x8 fa  = *(const bf16x8*)(Phi + phi_blk(cq, q + 4 * kbF));
            const bf16_t* pb = phN + (size_t)(kbF * 32) * 512;
            const bf16x8 fb0 = *(const bf16x8*)(pb);
            const bf16x8 fb1 = *(const bf16x8*)(pb + 512);
            acc[0] = mfma16(fa, fb0, acc[0]);
            acc[1] = mfma16(fa, fb1, acc[1]);
        }

        // ---- stage Dv(ccn) into Dvl: overlapped with final-kb + next dump,
        //      visible at the next barrier A ----
        if (hasN) {
            const float* src = Dv + (((size_t)ccn * 16 + w) << 9) + 8 * lane;
            const float4 a = *(const float4*)(src);
            const float4 b = *(const float4*)(src + 4);
            float* dst = Dvl + w * 512 + 8 * lane;
            *(float4*)(dst)     = a;
            *(float4*)(dst + 4) = b;
        }
    }

    // ---- epilogue: wave w reads rotated blocks of its row, writes coalesced --
    {
        float* orow = out + (size_t)(b0 + w) * V + lane * 8;
        const bf16x8 o = *(const bf16x8*)(Phi + phi_blk(w, lane));
        float4 o0, o1;
        o0.x = (float)o[0]; o0.y = (float)o[1];
        o0.z = (float)o[2]; o0.w = (float)o[3];
        o1.x = (float)o[4]; o1.y = (float)o[5];
        o1.z = (float)o[6]; o1.w = (float)o[7];
        *(float4*)(orow)     = o0;
        *(float4*)(orow + 4) = o1;
    }
}

extern "C" void kernel_launch(void* const* d_in, const int* in_sizes, int n_in,
                              void* d_out, int out_size, void* d_ws, size_t ws_size,
                              hipStream_t stream) {
    const float* preds = (const float*)d_in[0];
    const float* pos   = (const float*)d_in[1];
    const float* neg   = (const float*)d_in[2];
    float* o = (float*)d_out;
    char* base = (char*)d_ws;
    bf16_t* Mhi = (bf16_t*)base;
    float*  Dv  = (float*)(base + DV_OFF);
    float*  Bv  = (float*)(base + BV_OFF);
    repack_all<<<dim3(528), 1024, 0, stream>>>(pos, neg, Mhi, Dv, Bv);
    shield_fused<<<dim3(BATCH / RB), NT, 0, stream>>>(preds, Mhi, Dv, Bv, o);
}

// Round 14
// 355.591 us; speedup vs baseline: 1.2775x; 1.0717x over previous
//
#include <hip/hip_runtime.h>

#define BATCH 8192
#define V 512
#define N1 513
#define KCH 16
#define NCHUNKS 32
#define RB 16            // rows per block -> grid 512 = 2 blocks/CU, 32 waves/CU
#define NT 1024          // 16 waves; each wave owns ONE chain row
#define PKS 520          // Phi row stride (bf16 elems)
#define SJ2 516          // S row stride (dwords)

typedef __bf16 bf16_t;
typedef bf16_t bf16x8 __attribute__((ext_vector_type(8)));
typedef float f32x4 __attribute__((ext_vector_type(4)));

// workspace: Mhi (fragment-linear triangular pack, mat=1 tiles PRE-NEGATED),
// Dv (fp32, pre-scaled by mat sign), Bv (fp32, pre-negated mat=1).
#define EPP 4194304ull
#define DV_OFF (EPP * 2ull)
#define BV_OFF (DV_OFF + 1048576ull)

__device__ __forceinline__ f32x4 mfma16(bf16x8 a, bf16x8 b, f32x4 c) {
    return __builtin_amdgcn_mfma_f32_16x16x32_bf16(a, b, c, 0, 0, 0);
}

__device__ __forceinline__ float bcast_lane(float x, int l) {
    return __int_as_float(__builtin_amdgcn_readlane(__float_as_int(x), l));
}

__device__ __forceinline__ float dpp_xor1_max(float x) {
    const int xi = __float_as_int(x);
    const float o = __int_as_float(
        __builtin_amdgcn_update_dpp(xi, xi, 0xB1, 0xF, 0xF, false));
    return fmaxf(x, o);
}

// ---- unified repack (R5 structure + vectorized b128 Mhi gather, per R12) ---
__global__ __launch_bounds__(1024)
void repack_all(const float* __restrict__ pos, const float* __restrict__ neg,
                bf16_t* __restrict__ Mhi, float* __restrict__ Dv,
                float* __restrict__ Bv)
{
    __shared__ float sb[2 * 256 * 36];   // 73,728 B
    const int bx  = blockIdx.x;
    const int tid = threadIdx.x;
    if (bx < 496) {
        const int cc  = (bx >> 4) + 1;       // 1..31
        const int kb  = bx & 15;
        const int nkb = (cc + 1) >> 1;
        if (kb >= nkb) return;
        const int klen = 16 * cc;
        for (int idx = tid; idx < 8192; idx += 1024) {
            const int r = idx >> 5, k32 = idx & 31;
            const int k = kb * 32 + k32;
            const size_t row = (size_t)cc * 256 + r;
            float xp = 0.0f, xn = 0.0f;
            if (k < klen) {
                xp = pos[row * N1 + k];
                xn = -neg[row * N1 + k];     // pre-negate mat=1
            }
            sb[r * 36 + k32]            = xp;
            sb[256 * 36 + r * 36 + k32] = xn;
        }
        __syncthreads();
        const size_t base = 16384ull * (size_t)((cc * cc) / 4) + (size_t)kb * 16384ull;
        for (int e8 = tid; e8 < 2048; e8 += 1024) {
            const int t = e8 >> 6, s = e8 & 63;
            const int c = s & 15, q = s >> 4;
            const int vloc = t >> 1, m = t & 1;
            // 16B-aligned gather: (vloc*16+c)*36 + 8q ≡ 0 mod 4
            const float* sp = &sb[m * 256 * 36 + (vloc * 16 + c) * 36 + 8 * q];
            const float4 f0 = *(const float4*)(sp);
            const float4 f1 = *(const float4*)(sp + 4);
            bf16x8 o;
            o[0] = (bf16_t)f0.x; o[1] = (bf16_t)f0.y;
            o[2] = (bf16_t)f0.z; o[3] = (bf16_t)f0.w;
            o[4] = (bf16_t)f1.x; o[5] = (bf16_t)f1.y;
            o[6] = (bf16_t)f1.z; o[7] = (bf16_t)f1.w;
            *(bf16x8*)(Mhi + base + (size_t)e8 * 8) = o;
        }
    } else {
        const int cc = bx - 496;             // 0..31, one block per chunk
        float* bufP = sb;                    // stride-17 views
        float* bufN = sb + 256 * 17;
        for (int idx = tid; idx < 4096; idx += 1024) {
            const int r = idx >> 4, kk = idx & 15;
            const size_t row = (size_t)(cc * 256 + r);
            bufP[r * 17 + kk] = pos[row * N1 + cc * 16 + kk];
            bufN[r * 17 + kk] = neg[row * N1 + cc * 16 + kk];
        }
        __syncthreads();
        for (int idx = tid; idx < 8192; idx += 1024) {
            const int vl = idx >> 9, j = idx & 511;
            const int vlo = j >> 5, c = j & 15;
            const int m = (j >> 4) & 1;
            const float x = (m ? bufN : bufP)[(vlo * 16 + c) * 17 + vl];
            Dv[(size_t)cc * 8192 + idx] = m ? -x : x;
        }
        for (int j = tid; j < 512; j += 1024) {
            const int vlo = j >> 5, c = j & 15;
            const int m = (j >> 4) & 1;
            const float* src = m ? neg : pos;
            const float x = src[(size_t)(cc * 256 + vlo * 16 + c) * N1 + V];
            Bv[(size_t)cc * 512 + j] = m ? -x : x;
        }
    }
}

// ---- fused main kernel (exact R7, the measured optimum: 307 us) --------------
// Ledger: R7=307; R8 swizzle 310 (null), R9 32-row+dedup 322, R10 async-LDS
// 361, R11 fat-wave 400, R12 2-barrier 358, R13 +rotation 333 (spill). R7 sits
// at the joint constraint: 32 waves/CU (LDS-capped max), 64 VGPR/wave wall
// (any cross-step state spills), dv/s2 LDS patterns at data-volume minimum,
// and all latency-cover mechanisms either spill (regs) or serialize (vmcnt).
// Structure per chunk: dump acc->S, barA, s2-load + po-prefetch, barB,
// stage Dv->dead S region, barC, 16-step chain (dv from LDS) + interleaved
// GEMM of chunk cc+1, barD, final k-block.
__global__ __launch_bounds__(NT, 8)
void shield_fused(const float* __restrict__ preds,
                  const bf16_t* __restrict__ Mhi,
                  const float* __restrict__ Dv, const float* __restrict__ Bv,
                  float* __restrict__ out)
{
    __shared__ bf16_t Phi[RB * PKS];   // 16,640 B
    __shared__ float  S[RB * SJ2];     // 33,024 B; aliased as Dv_lds[16][512]
                                       // total 49,664 -> 2 blocks/CU

    const int tid  = threadIdx.x;
    const int b0   = blockIdx.x * RB;
    const int lane = tid & 63;
    const int w    = tid >> 6;          // 0..15; chain row = w
    const int cq   = lane & 15;
    const int q    = lane >> 4;

    // ---- load preds -> Phi: wave w loads its row, 8 cols/lane, coalesced ----
    {
        const float* prow = preds + (size_t)(b0 + w) * V + lane * 8;
        const float4 p0 = *(const float4*)(prow);
        const float4 p1 = *(const float4*)(prow + 4);
        const int n = lane * 8;
        Phi[w * PKS + n + 0] = (bf16_t)p0.x;
        Phi[w * PKS + n + 1] = (bf16_t)p0.y;
        Phi[w * PKS + n + 2] = (bf16_t)p0.z;
        Phi[w * PKS + n + 3] = (bf16_t)p0.w;
        Phi[w * PKS + n + 4] = (bf16_t)p1.x;
        Phi[w * PKS + n + 5] = (bf16_t)p1.y;
        Phi[w * PKS + n + 6] = (bf16_t)p1.z;
        Phi[w * PKS + n + 7] = (bf16_t)p1.w;
    }

    int tJ[2];
    #pragma unroll
    for (int tt = 0; tt < 2; ++tt) tJ[tt] = ((2 * w + tt) << 4) + cq;
    const int aoff = cq * PKS + 8 * q;

    // acc(0) = bias(0)
    f32x4 acc[2];
    #pragma unroll
    for (int tt = 0; tt < 2; ++tt) {
        const float b = Bv[tJ[tt]];
        acc[tt] = f32x4{b, b, b, b};
    }

    #pragma unroll 1
    for (int cc = 0; cc < NCHUNKS; ++cc) {
        const int v0 = cc * 16;
        const int  ccn  = cc + 1;
        const bool hasN = ccn < NCHUNKS;
        const int  nkbN = hasN ? ((ccn + 1) >> 1) : 0;
        const bf16_t* phN = Mhi + 16384ull * (size_t)((ccn * ccn) / 4)
                          + (size_t)lane * 8 + (size_t)(2 * w) * 512;

        // ---- dump acc(cc) -> S ----
        #pragma unroll
        for (int tt = 0; tt < 2; ++tt)
            #pragma unroll
            for (int reg = 0; reg < 4; ++reg)
                S[(4 * q + reg) * SJ2 + tJ[tt]] = acc[tt][reg];
        __syncthreads();   // (A) S ready; prior Phi writes visible

        // ---- load s2: lane owns j = 8*lane..8*lane+7 of row w ----
        float s2[8];
        {
            const float* sp = &S[w * SJ2 + 8 * lane];
            const float4 a0 = *(const float4*)(sp);
            const float4 a1 = *(const float4*)(sp + 4);
            s2[0] = a0.x; s2[1] = a0.y; s2[2] = a0.z; s2[3] = a0.w;
            s2[4] = a1.x; s2[5] = a1.y; s2[6] = a1.z; s2[7] = a1.w;
        }

        // ---- po prefetch: cols v0..v0+15 of row w (each col read only at
        // its own step; the correcting write is by this same wave) ----
        const bf16x8 po0 = *(const bf16x8*)(Phi + w * PKS + v0);
        const bf16x8 po1 = *(const bf16x8*)(Phi + w * PKS + v0 + 8);

        // ---- init acc(ccn) with bias ----
        if (hasN) {
            #pragma unroll
            for (int tt = 0; tt < 2; ++tt) {
                const float b = Bv[(ccn << 9) + tJ[tt]];
                acc[tt] = f32x4{b, b, b, b};
            }
        }

        __syncthreads();   // (B) all s2 reads done; S region reusable

        // ---- stage Dv(cc) into the dead S region: wave w stages row w ----
        {
            const float* src = Dv + (((size_t)cc * 16 + w) << 9) + 8 * lane;
            const float4 a = *(const float4*)(src);
            const float4 b = *(const float4*)(src + 4);
            float* dst = S + w * 512 + 8 * lane;
            *(float4*)(dst)     = a;
            *(float4*)(dst + 4) = b;
        }
        __syncthreads();   // (C) Dv_lds ready

        // ---- 16-step serial chain + interleaved bulk GEMM of chunk ccn ----
        #pragma unroll
        for (int vl = 0; vl < KCH; ++vl) {
            const int vcur = v0 + vl;
            const bool doKb = hasN && (vl < nkbN - 1);

            bf16x8 fa, fb0, fb1;
            if (doKb) {
                const int k0 = vl * 32;
                fa  = *(const bf16x8*)(Phi + aoff + k0);
                const bf16_t* pb = phN + (size_t)k0 * 512;
                fb0 = *(const bf16x8*)(pb);
                fb1 = *(const bf16x8*)(pb + 512);
            }

            // this step's dv from LDS (shared across all 16 waves)
            float dv[8];
            {
                const float* dls = S + vl * 512 + 8 * lane;
                const float4 d0 = *(const float4*)(dls);
                const float4 d1 = *(const float4*)(dls + 4);
                dv[0]=d0.x; dv[1]=d0.y; dv[2]=d0.z; dv[3]=d0.w;
                dv[4]=d1.x; dv[5]=d1.y; dv[6]=d1.z; dv[7]=d1.w;
            }
            const float po = (float)(vl < 8 ? po0[vl & 7] : po1[vl & 7]);

            // in-lane reduce 8 -> 1 (max3-fusable), xor-1 merge via DPP
            const float m0 = fmaxf(fmaxf(s2[0], s2[1]), s2[2]);
            const float m1 = fmaxf(fmaxf(s2[3], s2[4]), s2[5]);
            const float m2 = fmaxf(s2[6], s2[7]);
            const float red = dpp_xor1_max(fmaxf(fmaxf(m0, m1), m2));
            // broadcast from compile-time lanes via v_readlane (no DS op)
            const float lw  = bcast_lane(red, 4 * vl);       // lower
            const float nup = bcast_lane(red, 4 * vl + 2);   // -upper
            const float pc  = fminf(fmaxf(po, lw), -nup);
            if (lane == 4 * vl) Phi[w * PKS + vcur] = (bf16_t)pc;

            // rank-1 update (Dv pre-scaled so no sign mul)
            #pragma unroll
            for (int jj = 0; jj < 8; ++jj) s2[jj] = fmaf(dv[jj], pc, s2[jj]);

            if (doKb) {
                acc[0] = mfma16(fa, fb0, acc[0]);
                acc[1] = mfma16(fa, fb1, acc[1]);
            }
        }

        __syncthreads();   // (D) fresh Phi visible; S safe for next dump

        // ---- final k-block of chunk ccn (zero-padded B -> exact no-ops) ----
        if (hasN) {
            const int k0 = (nkbN - 1) * 32;
            const bf16x8 fa  = *(const bf16x8*)(Phi + aoff + k0);
            const bf16_t* pb = phN + (size_t)k0 * 512;
            const bf16x8 fb0 = *(const bf16x8*)(pb);
            const bf16x8 fb1 = *(const bf16x8*)(pb + 512);
            acc[0] = mfma16(fa, fb0, acc[0]);
            acc[1] = mfma16(fa, fb1, acc[1]);
        }
    }

    // ---- epilogue: wave w writes its row, 8 cols/lane, coalesced ----
    {
        float* orow = out + (size_t)(b0 + w) * V + lane * 8;
        const int n = lane * 8;
        float4 o0, o1;
        o0.x = (float)Phi[w * PKS + n + 0];
        o0.y = (float)Phi[w * PKS + n + 1];
        o0.z = (float)Phi[w * PKS + n + 2];
        o0.w = (float)Phi[w * PKS + n + 3];
        o1.x = (float)Phi[w * PKS + n + 4];
        o1.y = (float)Phi[w * PKS + n + 5];
        o1.z = (float)Phi[w * PKS + n + 6];
        o1.w = (float)Phi[w * PKS + n + 7];
        *(float4*)(orow)     = o0;
        *(float4*)(orow + 4) = o1;
    }
}

extern "C" void kernel_launch(void* const* d_in, const int* in_sizes, int n_in,
                              void* d_out, int out_size, void* d_ws, size_t ws_size,
                              hipStream_t stream) {
    const float* preds = (const float*)d_in[0];
    const float* pos   = (const float*)d_in[1];
    const float* neg   = (const float*)d_in[2];
    float* o = (float*)d_out;
    char* base = (char*)d_ws;
    bf16_t* Mhi = (bf16_t*)base;
    float*  Dv  = (float*)(base + DV_OFF);
    float*  Bv  = (float*)(base + BV_OFF);
    repack_all<<<dim3(528), 1024, 0, stream>>>(pos, neg, Mhi, Dv, Bv);
    shield_fused<<<dim3(BATCH / RB), NT, 0, stream>>>(preds, Mhi, Dv, Bv, o);
}

// Round 15
// 355.507 us; speedup vs baseline: 1.2778x; 1.0002x over previous
//
#include <hip/hip_runtime.h>

#define BATCH 8192
#define V 512
#define N1 513
#define KCH 16
#define NCHUNKS 32
#define RB 16            // rows per block -> grid 512 = 2 blocks/CU, 32 waves/CU
#define NT 1024          // 16 waves; each wave owns ONE chain row
#define PKS 520          // Phi row stride (bf16 elems)
#define SJ2 516          // S row stride (dwords)

typedef __bf16 bf16_t;
typedef bf16_t bf16x8 __attribute__((ext_vector_type(8)));
typedef float f32x4 __attribute__((ext_vector_type(4)));
// 4B-aligned float4: N1=513 rows are only dword-aligned; AMD global dwordx4
// loads need only 4B alignment, so this is legal and 4x fewer instructions.
typedef float f4u __attribute__((ext_vector_type(4), aligned(4)));

// workspace: Mhi (fragment-linear triangular pack, mat=1 tiles PRE-NEGATED),
// Dv (fp32, pre-scaled by mat sign), Bv (fp32, pre-negated mat=1).
#define EPP 4194304ull
#define DV_OFF (EPP * 2ull)
#define BV_OFF (DV_OFF + 1048576ull)

__device__ __forceinline__ f32x4 mfma16(bf16x8 a, bf16x8 b, f32x4 c) {
    return __builtin_amdgcn_mfma_f32_16x16x32_bf16(a, b, c, 0, 0, 0);
}

__device__ __forceinline__ float bcast_lane(float x, int l) {
    return __int_as_float(__builtin_amdgcn_readlane(__float_as_int(x), l));
}

__device__ __forceinline__ float dpp_xor1_max(float x) {
    const int xi = __float_as_int(x);
    const float o = __int_as_float(
        __builtin_amdgcn_update_dpp(xi, xi, 0xB1, 0xF, 0xF, false));
    return fmaxf(x, o);
}

// ---- unified repack R15: staging global loads vectorized to dwordx4 ----------
// (values, LDS layouts, outputs bit-identical to R14; only load width changes)
__global__ __launch_bounds__(1024)
void repack_all(const float* __restrict__ pos, const float* __restrict__ neg,
                bf16_t* __restrict__ Mhi, float* __restrict__ Dv,
                float* __restrict__ Bv)
{
    __shared__ float sb[2 * 256 * 36];   // 73,728 B
    const int bx  = blockIdx.x;
    const int tid = threadIdx.x;
    if (bx < 496) {
        const int cc  = (bx >> 4) + 1;       // 1..31
        const int kb  = bx & 15;
        const int nkb = (cc + 1) >> 1;
        if (kb >= nkb) return;
        const int klen = 16 * cc;
        // stage 256 rows x 32 cols of pos/neg, float4 loads (klen%16==0 and
        // k%4==0 -> a float4 is entirely in- or out-of-range)
        for (int idx = tid; idx < 2048; idx += 1024) {
            const int r = idx >> 3, k4 = (idx & 7) << 2;
            const int k = kb * 32 + k4;
            const size_t row = (size_t)cc * 256 + r;
            f4u xp = {0.0f, 0.0f, 0.0f, 0.0f};
            f4u xn = {0.0f, 0.0f, 0.0f, 0.0f};
            if (k < klen) {
                xp = *(const f4u*)(pos + row * N1 + k);
                const f4u t = *(const f4u*)(neg + row * N1 + k);
                xn = f4u{-t[0], -t[1], -t[2], -t[3]};   // pre-negate mat=1
            }
            // sb row stride 36: (36r + k4)*4B ≡ 0 mod 16 -> aligned b128 write
            *(f4u*)(&sb[r * 36 + k4])            = xp;
            *(f4u*)(&sb[256 * 36 + r * 36 + k4]) = xn;
        }
        __syncthreads();
        const size_t base = 16384ull * (size_t)((cc * cc) / 4) + (size_t)kb * 16384ull;
        for (int e8 = tid; e8 < 2048; e8 += 1024) {
            const int t = e8 >> 6, s = e8 & 63;
            const int c = s & 15, q = s >> 4;
            const int vloc = t >> 1, m = t & 1;
            // 16B-aligned gather: (vloc*16+c)*36 + 8q ≡ 0 mod 4
            const float* sp = &sb[m * 256 * 36 + (vloc * 16 + c) * 36 + 8 * q];
            const float4 f0 = *(const float4*)(sp);
            const float4 f1 = *(const float4*)(sp + 4);
            bf16x8 o;
            o[0] = (bf16_t)f0.x; o[1] = (bf16_t)f0.y;
            o[2] = (bf16_t)f0.z; o[3] = (bf16_t)f0.w;
            o[4] = (bf16_t)f1.x; o[5] = (bf16_t)f1.y;
            o[6] = (bf16_t)f1.z; o[7] = (bf16_t)f1.w;
            *(bf16x8*)(Mhi + base + (size_t)e8 * 8) = o;
        }
    } else {
        const int cc = bx - 496;             // 0..31, one block per chunk
        float* bufP = sb;                    // stride-17 views
        float* bufN = sb + 256 * 17;
        // stage 256 rows x 16 cols: float4 global loads, scalar LDS writes
        // (stride 17 kept: conflict-free transposed read; writes are cheap)
        for (int idx = tid; idx < 1024; idx += 1024) {
            const int r = idx >> 2, kk0 = (idx & 3) << 2;
            const size_t row = (size_t)(cc * 256 + r);
            const f4u p = *(const f4u*)(pos + row * N1 + cc * 16 + kk0);
            const f4u n = *(const f4u*)(neg + row * N1 + cc * 16 + kk0);
            #pragma unroll
            for (int u = 0; u < 4; ++u) {
                bufP[r * 17 + kk0 + u] = p[u];
                bufN[r * 17 + kk0 + u] = n[u];
            }
        }
        __syncthreads();
        // Dv: [vl][512 j], writes coalesced, reads from LDS transpose
        for (int idx = tid; idx < 8192; idx += 1024) {
            const int vl = idx >> 9, j = idx & 511;
            const int vlo = j >> 5, c = j & 15;
            const int m = (j >> 4) & 1;
            const float x = (m ? bufN : bufP)[(vlo * 16 + c) * 17 + vl];
            Dv[(size_t)cc * 8192 + idx] = m ? -x : x;
        }
        // Bv: 512 per chunk (bias column), tiny scattered read is fine
        for (int j = tid; j < 512; j += 1024) {
            const int vlo = j >> 5, c = j & 15;
            const int m = (j >> 4) & 1;
            const float* src = m ? neg : pos;
            const float x = src[(size_t)(cc * 256 + vlo * 16 + c) * N1 + V];
            Bv[(size_t)cc * 512 + j] = m ? -x : x;
        }
    }
}

// ---- fused main kernel (exact R7/R14, the measured optimum: ~310 us) ---------
// Ledger: R7=307; R8 swizzle 310 (null), R9 32-row+dedup 322, R10 async-LDS
// 361, R11 fat-wave 400, R12 2-barrier 358, R13 +rotation 333 (spill). R7 sits
// at the joint constraint: 32 waves/CU (LDS-capped max), 64 VGPR/wave wall
// (any cross-step state spills), dv/s2 LDS patterns at data-volume minimum,
// and all latency-cover mechanisms either spill (regs) or serialize (vmcnt).
// Per-step window arithmetic: L1 fb ~1000cy, VALU ~880cy, LDS ~900cy in a
// 1440cy window -- three pipes at 60-70%, no single-pipe roofline. DO NOT EDIT.
__global__ __launch_bounds__(NT, 8)
void shield_fused(const float* __restrict__ preds,
                  const bf16_t* __restrict__ Mhi,
                  const float* __restrict__ Dv, const float* __restrict__ Bv,
                  float* __restrict__ out)
{
    __shared__ bf16_t Phi[RB * PKS];   // 16,640 B
    __shared__ float  S[RB * SJ2];     // 33,024 B; aliased as Dv_lds[16][512]
                                       // total 49,664 -> 2 blocks/CU

    const int tid  = threadIdx.x;
    const int b0   = blockIdx.x * RB;
    const int lane = tid & 63;
    const int w    = tid >> 6;          // 0..15; chain row = w
    const int cq   = lane & 15;
    const int q    = lane >> 4;

    // ---- load preds -> Phi: wave w loads its row, 8 cols/lane, coalesced ----
    {
        const float* prow = preds + (size_t)(b0 + w) * V + lane * 8;
        const float4 p0 = *(const float4*)(prow);
        const float4 p1 = *(const float4*)(prow + 4);
        const int n = lane * 8;
        Phi[w * PKS + n + 0] = (bf16_t)p0.x;
        Phi[w * PKS + n + 1] = (bf16_t)p0.y;
        Phi[w * PKS + n + 2] = (bf16_t)p0.z;
        Phi[w * PKS + n + 3] = (bf16_t)p0.w;
        Phi[w * PKS + n + 4] = (bf16_t)p1.x;
        Phi[w * PKS + n + 5] = (bf16_t)p1.y;
        Phi[w * PKS + n + 6] = (bf16_t)p1.z;
        Phi[w * PKS + n + 7] = (bf16_t)p1.w;
    }

    int tJ[2];
    #pragma unroll
    for (int tt = 0; tt < 2; ++tt) tJ[tt] = ((2 * w + tt) << 4) + cq;
    const int aoff = cq * PKS + 8 * q;

    // acc(0) = bias(0)
    f32x4 acc[2];
    #pragma unroll
    for (int tt = 0; tt < 2; ++tt) {
        const float b = Bv[tJ[tt]];
        acc[tt] = f32x4{b, b, b, b};
    }

    #pragma unroll 1
    for (int cc = 0; cc < NCHUNKS; ++cc) {
        const int v0 = cc * 16;
        const int  ccn  = cc + 1;
        const bool hasN = ccn < NCHUNKS;
        const int  nkbN = hasN ? ((ccn + 1) >> 1) : 0;
        const bf16_t* phN = Mhi + 16384ull * (size_t)((ccn * ccn) / 4)
                          + (size_t)lane * 8 + (size_t)(2 * w) * 512;

        // ---- dump acc(cc) -> S ----
        #pragma unroll
        for (int tt = 0; tt < 2; ++tt)
            #pragma unroll
            for (int reg = 0; reg < 4; ++reg)
                S[(4 * q + reg) * SJ2 + tJ[tt]] = acc[tt][reg];
        __syncthreads();   // (A) S ready; prior Phi writes visible

        // ---- load s2: lane owns j = 8*lane..8*lane+7 of row w ----
        float s2[8];
        {
            const float* sp = &S[w * SJ2 + 8 * lane];
            const float4 a0 = *(const float4*)(sp);
            const float4 a1 = *(const float4*)(sp + 4);
            s2[0] = a0.x; s2[1] = a0.y; s2[2] = a0.z; s2[3] = a0.w;
            s2[4] = a1.x; s2[5] = a1.y; s2[6] = a1.z; s2[7] = a1.w;
        }

        // ---- po prefetch: cols v0..v0+15 of row w (each col read only at
        // its own step; the correcting write is by this same wave) ----
        const bf16x8 po0 = *(const bf16x8*)(Phi + w * PKS + v0);
        const bf16x8 po1 = *(const bf16x8*)(Phi + w * PKS + v0 + 8);

        // ---- init acc(ccn) with bias ----
        if (hasN) {
            #pragma unroll
            for (int tt = 0; tt < 2; ++tt) {
                const float b = Bv[(ccn << 9) + tJ[tt]];
                acc[tt] = f32x4{b, b, b, b};
            }
        }

        __syncthreads();   // (B) all s2 reads done; S region reusable

        // ---- stage Dv(cc) into the dead S region: wave w stages row w ----
        {
            const float* src = Dv + (((size_t)cc * 16 + w) << 9) + 8 * lane;
            const float4 a = *(const float4*)(src);
            const float4 b = *(const float4*)(src + 4);
            float* dst = S + w * 512 + 8 * lane;
            *(float4*)(dst)     = a;
            *(float4*)(dst + 4) = b;
        }
        __syncthreads();   // (C) Dv_lds ready

        // ---- 16-step serial chain + interleaved bulk GEMM of chunk ccn ----
        #pragma unroll
        for (int vl = 0; vl < KCH; ++vl) {
            const int vcur = v0 + vl;
            const bool doKb = hasN && (vl < nkbN - 1);

            bf16x8 fa, fb0, fb1;
            if (doKb) {
                const int k0 = vl * 32;
                fa  = *(const bf16x8*)(Phi + aoff + k0);
                const bf16_t* pb = phN + (size_t)k0 * 512;
                fb0 = *(const bf16x8*)(pb);
                fb1 = *(const bf16x8*)(pb + 512);
            }

            // this step's dv from LDS (shared across all 16 waves)
            float dv[8];
            {
                const float* dls = S + vl * 512 + 8 * lane;
                const float4 d0 = *(const float4*)(dls);
                const float4 d1 = *(const float4*)(dls + 4);
                dv[0]=d0.x; dv[1]=d0.y; dv[2]=d0.z; dv[3]=d0.w;
                dv[4]=d1.x; dv[5]=d1.y; dv[6]=d1.z; dv[7]=d1.w;
            }
            const float po = (float)(vl < 8 ? po0[vl & 7] : po1[vl & 7]);

            // in-lane reduce 8 -> 1 (max3-fusable), xor-1 merge via DPP
            const float m0 = fmaxf(fmaxf(s2[0], s2[1]), s2[2]);
            const float m1 = fmaxf(fmaxf(s2[3], s2[4]), s2[5]);
            const float m2 = fmaxf(s2[6], s2[7]);
            const float red = dpp_xor1_max(fmaxf(fmaxf(m0, m1), m2));
            // broadcast from compile-time lanes via v_readlane (no DS op)
            const float lw  = bcast_lane(red, 4 * vl);       // lower
            const float nup = bcast_lane(red, 4 * vl + 2);   // -upper
            const float pc  = fminf(fmaxf(po, lw), -nup);
            if (lane == 4 * vl) Phi[w * PKS + vcur] = (bf16_t)pc;

            // rank-1 update (Dv pre-scaled so no sign mul)
            #pragma unroll
            for (int jj = 0; jj < 8; ++jj) s2[jj] = fmaf(dv[jj], pc, s2[jj]);

            if (doKb) {
                acc[0] = mfma16(fa, fb0, acc[0]);
                acc[1] = mfma16(fa, fb1, acc[1]);
            }
        }

        __syncthreads();   // (D) fresh Phi visible; S safe for next dump

        // ---- final k-block of chunk ccn (zero-padded B -> exact no-ops) ----
        if (hasN) {
            const int k0 = (nkbN - 1) * 32;
            const bf16x8 fa  = *(const bf16x8*)(Phi + aoff + k0);
            const bf16_t* pb = phN + (size_t)k0 * 512;
            const bf16x8 fb0 = *(const bf16x8*)(pb);
            const bf16x8 fb1 = *(const bf16x8*)(pb + 512);
            acc[0] = mfma16(fa, fb0, acc[0]);
            acc[1] = mfma16(fa, fb1, acc[1]);
        }
    }

    // ---- epilogue: wave w writes its row, 8 cols/lane, coalesced ----
    {
        float* orow = out + (size_t)(b0 + w) * V + lane * 8;
        const int n = lane * 8;
        float4 o0, o1;
        o0.x = (float)Phi[w * PKS + n + 0];
        o0.y = (float)Phi[w * PKS + n + 1];
        o0.z = (float)Phi[w * PKS + n + 2];
        o0.w = (float)Phi[w * PKS + n + 3];
        o1.x = (float)Phi[w * PKS + n + 4];
        o1.y = (float)Phi[w * PKS + n + 5];
        o1.z = (float)Phi[w * PKS + n + 6];
        o1.w = (float)Phi[w * PKS + n + 7];
        *(float4*)(orow)     = o0;
        *(float4*)(orow + 4) = o1;
    }
}

extern "C" void kernel_launch(void* const* d_in, const int* in_sizes, int n_in,
                              void* d_out, int out_size, void* d_ws, size_t ws_size,
                              hipStream_t stream) {
    const float* preds = (const float*)d_in[0];
    const float* pos   = (const float*)d_in[1];
    const float* neg   = (const float*)d_in[2];
    float* o = (float*)d_out;
    char* base = (char*)d_ws;
    bf16_t* Mhi = (bf16_t*)base;
    float*  Dv  = (float*)(base + DV_OFF);
    float*  Bv  = (float*)(base + BV_OFF);
    repack_all<<<dim3(528), 1024, 0, stream>>>(pos, neg, Mhi, Dv, Bv);
    shield_fused<<<dim3(BATCH / RB), NT, 0, stream>>>(preds, Mhi, Dv, Bv, o);
}